// Round 15
// baseline (3908.386 us; speedup 1.0000x reference)
//
#include <hip/hip_runtime.h>
#include <hip/hip_bf16.h>

typedef __attribute__((ext_vector_type(8))) short bf16x8;
typedef __attribute__((ext_vector_type(4))) float f32x4;

#define T_STEPS 256
#define BATCH   64
#define KDIM    1024
#define HDIM    1024
#define NGATE   3072   // 3*HDIM
#define LAYERS  3
#define SLOTE   (BATCH * HDIM)       // elements per h slot
#define RING_SLOTS (T_STEPS + 1)
#define WSZ     (192L * 32 * 64 * 8) // swizzled weight elems per layer
#define FSTRIDE 4                    // uints per flag (16 B padding)

#define LDS_BS_BYTES  65536                    // Whh r,z frags
#define LDS_WIS_BYTES 65536                    // Wih r,z frags
#define GI_PAR_FLOATS (3 * 64 * 20)            // padded [3][64][20] per parity
#define LDS_GI_BYTES  (2 * GI_PAR_FLOATS * 4)  // 30720 B
#define LDS_CTRL_OFF  (LDS_BS_BYTES + LDS_WIS_BYTES + LDS_GI_BYTES)
#define LDS_TOTAL     (LDS_CTRL_OFF + 64)      // 161856 <= 163840

#define MFMA16(a, b, c) __builtin_amdgcn_mfma_f32_16x16x32_bf16(a, b, c, 0, 0, 0)

// ---------- helpers (byte-identical to R6) ----------
__device__ __forceinline__ unsigned short f2b(float f) {
  union { float f; unsigned int u; } a; a.f = f;
  unsigned int u = a.u;
  unsigned int r = (u + 0x7FFFu + ((u >> 16) & 1u)) >> 16;  // RNE
  return (unsigned short)r;
}
__device__ __forceinline__ void gload16(const void* gptr, void* ldsptr) {
  __builtin_amdgcn_global_load_lds(
      (const __attribute__((address_space(1))) unsigned int*)gptr,
      (__attribute__((address_space(3))) unsigned int*)ldsptr,
      16, 0, 0);
}

// ---------- fp32 -> bf16 bulk convert (4 elems/thread) ----------
__global__ void f2b_kernel(const float* __restrict__ src,
                           unsigned short* __restrict__ dst, int n4) {
  int i = blockIdx.x * blockDim.x + threadIdx.x;
  if (i < n4) {
    float4 v = ((const float4*)src)[i];
    ushort4 o;
    o.x = f2b(v.x); o.y = f2b(v.y); o.z = f2b(v.z); o.w = f2b(v.w);
    ((ushort4*)dst)[i] = o;
  }
}

// ---------- swizzle a [3][3072][1024] fp32 matrix into MFMA frag layout ----------
// out: [l][ntile(192)][kc(32)][lane(64)][8 bf16]  (identical to R6..R13)
__global__ void swizzle_w(const float* __restrict__ w,
                          unsigned short* __restrict__ out) {
  long gid = (long)blockIdx.x * 256 + threadIdx.x;   // < 3*192*32*64
  int lane = (int)(gid & 63);
  long rest = gid >> 6;
  int kc = (int)(rest & 31); rest >>= 5;
  int ntile = (int)(rest % 192); int l = (int)(rest / 192);
  int n  = ntile * 16 + (lane & 15);
  int k0 = kc * 32 + (lane >> 4) * 8;
  const float* src = w + (((long)l * NGATE + n) * KDIM + k0);
  unsigned short o[8];
#pragma unroll
  for (int j = 0; j < 8; j++) o[j] = f2b(src[j]);
  bf16x8 v = *(bf16x8*)o;
  *(bf16x8*)(out + gid * 8) = v;
}

// ---------- fused 3-layer GRU, 192 wgs x 256 thr, fat-register waves ----------
// R14 = R9 step structure (single ring, single poll/drain/publish per step,
// same flag lattice) with the register budget to ACTUALLY batch loads:
//  * 4 waves/wg (w0,w1 = h; w2,w3 = x), 1 wave/SIMD, launch_bounds(256,1)
//    -> up to 512 VGPR/wave (R9's 128-cap forced the compiler to serialize
//    ha into dependent load groups; VGPR_Count=128 proved it).
//  * Each h-wave owns rows {w*16..+15} and {32+w*16..+15}: issues ALL 64 ha
//    frag loads up front (one LLC latency), then 192 MFMAs (Whh r,z LDS,
//    n regs). Each x-wave mirrors for gi(t+1).
//  * gi handshake: R12's verified monotone LDS counters, participants=2.
//    Safe at 1 wave/SIMD (spin can't steal issue from a co-resident worker
//    — R12's failure mode). gi padded [64][20] (verified 7x conflict cut).
//  * Unlike R13: NO half rings, NO doubled publishes — per-step sync count
//    identical to R9 (its structure is the only one that measured fast).
__global__ __launch_bounds__(256, 1) void gru_fused(
    const unsigned short* __restrict__ xb,     // [T][64][1024] bf16 layer-0 input
    const unsigned short* __restrict__ wswhh,  // [3][WSZ] swizzled Whh
    const unsigned short* __restrict__ wswih,  // [3][WSZ] swizzled Wih
    const float* __restrict__ bih,             // [3][3072]
    const float* __restrict__ bhh,             // [3][3072]
    const float* __restrict__ h0,              // [3][64][1024]
    unsigned short* __restrict__ rings,        // [3][257][64*1024] bf16 (blocked slots)
    float* __restrict__ hout,                  // [3][64][1024] = d_out
    unsigned int* __restrict__ flags)          // [3][64][FSTRIDE], memset 0
{
  extern __shared__ __align__(16) char smem[];
  unsigned short* Bs  = (unsigned short*)smem;                       // [64][512]
  unsigned short* Wis = (unsigned short*)(smem + LDS_BS_BYTES);      // [64][512]
  float* gi_lds = (float*)(smem + LDS_BS_BYTES + LDS_WIS_BYTES);     // [2][3][64][20]
  unsigned int* ctrl = (unsigned int*)(smem + LDS_CTRL_OFF);
  // ctrl[0]=harr  ctrl[2+p]=giready[p]  ctrl[4+p]=gidone[p]

  int l = blockIdx.x >> 6, g = blockIdx.x & 63;
  int tid = threadIdx.x, wave = tid >> 6, lane = tid & 63;
  int lg = lane >> 4;
  bool is_h = (wave < 2);
  int w = is_h ? wave : wave - 2;           // 16-row tile index within each 32-row half
  int row0 = w * 16 + (lane & 15);          // tile-0 row (0..31)
  int row1 = 32 + row0;                     // tile-1 row (32..63)
  int cb = g * 16 + lg * 4;                 // first of 4 consecutive output cols

  const unsigned short* whh_l = wswhh + (size_t)l * WSZ;
  const unsigned short* wih_l = wswih + (size_t)l * WSZ;
  unsigned short* ring_l = rings + (size_t)l * RING_SLOTS * SLOTE;
  const unsigned short* prev_ring = rings + (size_t)(l - 1) * RING_SLOTS * SLOTE;
  unsigned int* fl = flags + (size_t)l * 64 * FSTRIDE;
  const unsigned int* fp = flags + (size_t)(l > 0 ? (l - 1) : 0) * 64 * FSTRIDE;

  if (tid < 16) ctrl[tid] = 0;

  // ---- stage Whh r,z (p 0..63) and Wih r,z (p 64..127) into LDS ----
#pragma unroll
  for (int i = 0; i < 32; i++) {
    int p = wave + i * 4;                  // 0..127, 4 waves x 32
    int gate = (p >> 5) & 1;
    int kc = p & 31;
    const unsigned short* src = (p < 64)
        ? whh_l + ((((long)gate * 64 + g) * 32 + kc) * 64 + lane) * 8
        : wih_l + ((((long)gate * 64 + g) * 32 + kc) * 64 + lane) * 8;
    unsigned short* dst = (p < 64)
        ? &Bs[(size_t)p * 512 + (size_t)lane * 8]
        : &Wis[(size_t)(p - 64) * 512 + (size_t)lane * 8];
    gload16(src, dst);
  }

  // ---- gate-n weights in regs: Whh-n (h-waves) / Wih-n (x-waves) ----
  bf16x8 wn[32];
  {
    const unsigned short* base = is_h ? whh_l : wih_l;
#pragma unroll
    for (int kc = 0; kc < 32; kc++)
      wn[kc] = *(const bf16x8*)(base + ((((long)(2 * 64 + g)) * 32 + kc) * 64 + lane) * 8);
  }

  // ---- biases + h0 publish for both tiles (h-waves) ----
  float br_[4], bz_[4], bi_n[4], bh_n[4];
  float hS[2][4];
  if (is_h) {
    const float* bh_l = bhh + l * NGATE;
    const float* bi_l = bih + l * NGATE;
    float4 bhr4 = *(const float4*)(bh_l + 0 * HDIM + cb);
    float4 bhz4 = *(const float4*)(bh_l + 1 * HDIM + cb);
    float4 bhn4 = *(const float4*)(bh_l + 2 * HDIM + cb);
    float4 bir4 = *(const float4*)(bi_l + 0 * HDIM + cb);
    float4 biz4 = *(const float4*)(bi_l + 1 * HDIM + cb);
    float4 bin4 = *(const float4*)(bi_l + 2 * HDIM + cb);
    br_[0] = bir4.x + bhr4.x; br_[1] = bir4.y + bhr4.y; br_[2] = bir4.z + bhr4.z; br_[3] = bir4.w + bhr4.w;
    bz_[0] = biz4.x + bhz4.x; bz_[1] = biz4.y + bhz4.y; bz_[2] = biz4.z + bhz4.z; bz_[3] = biz4.w + bhz4.w;
    bi_n[0] = bin4.x; bi_n[1] = bin4.y; bi_n[2] = bin4.z; bi_n[3] = bin4.w;
    bh_n[0] = bhn4.x; bh_n[1] = bhn4.y; bh_n[2] = bhn4.z; bh_n[3] = bhn4.w;
    unsigned short* slotT = ring_l + (size_t)T_STEPS * SLOTE;
#pragma unroll
    for (int rt = 0; rt < 2; rt++) {
      int row = rt ? row1 : row0;
      float4 h4 = *(const float4*)(h0 + (size_t)l * SLOTE + (size_t)row * HDIM + cb);
      hS[rt][0] = h4.x; hS[rt][1] = h4.y; hS[rt][2] = h4.z; hS[rt][3] = h4.w;
      union { unsigned short us[4]; unsigned long long u; } pk;
#pragma unroll
      for (int r = 0; r < 4; r++) pk.us[r] = f2b(hS[rt][r]);
      __hip_atomic_store((unsigned long long*)(slotT + (size_t)g * 1024 + (size_t)row * 16 + lg * 4),
                         pk.u, __ATOMIC_RELAXED, __HIP_MEMORY_SCOPE_AGENT);
    }
  }

  // ---- x-GEMV for step tt, both tiles (x-waves) ----
  auto xgemv = [&](int tt) {
    int p = tt & 1;
    float* gbase = gi_lds + (size_t)p * GI_PAR_FLOATS;
    f32x4 acc[2][3];
#pragma unroll
    for (int rt = 0; rt < 2; rt++) {
      int row = rt ? row1 : row0;
      f32x4 air = {}, aiz = {}, ain = {};
      bf16x8 xa[32];
      if (l == 0) {
        const unsigned short* xa_b = xb + (size_t)tt * SLOTE + (size_t)row * KDIM + lg * 8;
#pragma unroll
        for (int kc = 0; kc < 32; kc++)
          xa[kc] = *(const bf16x8*)(xa_b + (size_t)kc * 32);
      } else {
        const unsigned short* xa_b = prev_ring + (size_t)(T_STEPS - 1 - tt) * SLOTE
                                     + (size_t)(lg >> 1) * 1024 + (size_t)row * 16 + (lg & 1) * 8;
#pragma unroll
        for (int kc = 0; kc < 32; kc++)
          xa[kc] = *(const bf16x8*)(xa_b + (size_t)kc * 2048);
      }
#pragma unroll
      for (int kc = 0; kc < 32; kc++) {
        bf16x8 wir = *(const bf16x8*)&Wis[(size_t)kc * 512 + (size_t)lane * 8];
        bf16x8 wiz = *(const bf16x8*)&Wis[(size_t)(32 + kc) * 512 + (size_t)lane * 8];
        air = MFMA16(wir, xa[kc], air);
        aiz = MFMA16(wiz, xa[kc], aiz);
        ain = MFMA16(wn[kc], xa[kc], ain);
      }
      acc[rt][0] = air; acc[rt][1] = aiz; acc[rt][2] = ain;
    }
    // overwrite guard: h consumed this parity's previous step (2 h-waves)
    while (__hip_atomic_load(&ctrl[4 + p], __ATOMIC_ACQUIRE,
                             __HIP_MEMORY_SCOPE_WORKGROUP) < 2u * (unsigned)(tt >> 1)) {}
#pragma unroll
    for (int rt = 0; rt < 2; rt++) {
      int row = rt ? row1 : row0;
      float* gp = gbase + (size_t)row * 20 + lg * 4;
      *(f32x4*)(gp + 0)    = acc[rt][0];
      *(f32x4*)(gp + 1280) = acc[rt][1];
      *(f32x4*)(gp + 2560) = acc[rt][2];
    }
    if (lane == 0)
      __hip_atomic_fetch_add(&ctrl[2 + p], 1u, __ATOMIC_RELEASE,
                             __HIP_MEMORY_SCOPE_WORKGROUP);
  };

  __syncthreads();   // prologue only: staging + h0 drained; ctrl zeroed
  if (tid == 0)
    __hip_atomic_store(&fl[g * FSTRIDE], 1u, __ATOMIC_RELAXED, __HIP_MEMORY_SCOPE_AGENT);

  if (is_h) {
    while (__hip_atomic_load(&fl[lane * FSTRIDE], __ATOMIC_RELAXED,
                             __HIP_MEMORY_SCOPE_AGENT) < 1u) {}
    asm volatile("" ::: "memory");
  } else {
    if (l > 0) {
      while (__hip_atomic_load(&fp[lane * FSTRIDE], __ATOMIC_RELAXED,
                               __HIP_MEMORY_SCOPE_AGENT) < 2u) {}
      asm volatile("" ::: "memory");
    }
    xgemv(0);
  }

#pragma unroll 1
  for (int t = 0; t < T_STEPS; t++) {
    if (is_h) {
      if (t > 0) {   // h(t) slot (T-t) written at step t-1, published as t+1
        while (__hip_atomic_load(&fl[lane * FSTRIDE], __ATOMIC_RELAXED,
                                 __HIP_MEMORY_SCOPE_AGENT) < (unsigned)(t + 1)) {}
        asm volatile("" ::: "memory");
      }
      // ---- issue ALL 64 ha loads up front (both tiles, one LLC latency) ----
      const unsigned short* slot = ring_l + (size_t)(T_STEPS - t) * SLOTE;
      const unsigned short* ha_b0 = slot + (size_t)(lg >> 1) * 1024 + (size_t)row0 * 16 + (lg & 1) * 8;
      const unsigned short* ha_b1 = slot + (size_t)(lg >> 1) * 1024 + (size_t)row1 * 16 + (lg & 1) * 8;
      bf16x8 ha0[32], ha1[32];
#pragma unroll
      for (int kc = 0; kc < 32; kc++) ha0[kc] = *(const bf16x8*)(ha_b0 + (size_t)kc * 2048);
#pragma unroll
      for (int kc = 0; kc < 32; kc++) ha1[kc] = *(const bf16x8*)(ha_b1 + (size_t)kc * 2048);

      // ---- gi(t) handshake + read (LDS; spin overlaps ha flight) ----
      int p = t & 1;
      while (__hip_atomic_load(&ctrl[2 + p], __ATOMIC_ACQUIRE,
                               __HIP_MEMORY_SCOPE_WORKGROUP) < 2u * (unsigned)((t >> 1) + 1)) {}
      const float* gbase = gi_lds + (size_t)p * GI_PAR_FLOATS;
      f32x4 xi[2][3];
#pragma unroll
      for (int rt = 0; rt < 2; rt++) {
        const float* gp = gbase + (size_t)(rt ? row1 : row0) * 20 + lg * 4;
        xi[rt][0] = *(const f32x4*)(gp + 0);
        xi[rt][1] = *(const f32x4*)(gp + 1280);
        xi[rt][2] = *(const f32x4*)(gp + 2560);
      }
      asm volatile("s_waitcnt lgkmcnt(0)" ::: "memory");
      __builtin_amdgcn_sched_barrier(0);
      if (lane == 0)
        __hip_atomic_fetch_add(&ctrl[4 + p], 1u, __ATOMIC_RELEASE,
                               __HIP_MEMORY_SCOPE_WORKGROUP);

      // ---- h GEMV both tiles: Whh r,z from LDS, n from regs ----
      f32x4 ar0 = {}, az0 = {}, an0 = {}, ar1 = {}, az1 = {}, an1 = {};
#pragma unroll
      for (int kc = 0; kc < 32; kc++) {
        bf16x8 whr = *(const bf16x8*)&Bs[(size_t)kc * 512 + (size_t)lane * 8];
        bf16x8 whz = *(const bf16x8*)&Bs[(size_t)(32 + kc) * 512 + (size_t)lane * 8];
        ar0 = MFMA16(whr, ha0[kc], ar0);
        az0 = MFMA16(whz, ha0[kc], az0);
        an0 = MFMA16(wn[kc], ha0[kc], an0);
        ar1 = MFMA16(whr, ha1[kc], ar1);
        az1 = MFMA16(whz, ha1[kc], az1);
        an1 = MFMA16(wn[kc], ha1[kc], an1);
      }

      // ---- gates + state update, both tiles ----
      unsigned short* hn = ring_l + (size_t)(T_STEPS - 1 - t) * SLOTE;
#pragma unroll
      for (int rt = 0; rt < 2; rt++) {
        f32x4 ahr = rt ? ar1 : ar0, ahz = rt ? az1 : az0, ahn = rt ? an1 : an0;
        int row = rt ? row1 : row0;
        union { unsigned short us[4]; unsigned long long u; } pk;
#pragma unroll
        for (int r = 0; r < 4; r++) {
          float xr = xi[rt][0][r] + ahr[r] + br_[r];
          float xz = xi[rt][1][r] + ahz[r] + bz_[r];
          float rr = 1.0f / (1.0f + __expf(-xr));
          float zz = 1.0f / (1.0f + __expf(-xz));
          float xn = (xi[rt][2][r] + bi_n[r]) + rr * (ahn[r] + bh_n[r]);
          float e2 = __expf(-2.0f * xn);
          float nn = (1.0f - e2) / (1.0f + e2);    // tanh
          float hv = (1.0f - zz) * nn + zz * hS[rt][r];
          hS[rt][r] = hv;
          pk.us[r] = f2b(hv);
        }
        __hip_atomic_store((unsigned long long*)(hn + (size_t)g * 1024 + (size_t)row * 16 + lg * 4),
                           pk.u, __ATOMIC_RELAXED, __HIP_MEMORY_SCOPE_AGENT);
        if (t == T_STEPS - 1) {
          float4 o; o.x = hS[rt][0]; o.y = hS[rt][1]; o.z = hS[rt][2]; o.w = hS[rt][3];
          *(float4*)(hout + (size_t)l * SLOTE + (size_t)row * HDIM + cb) = o;
        }
      }

      // ---- drain own stores; pair-arrive; wave0 publishes flag ----
      asm volatile("s_waitcnt vmcnt(0)" ::: "memory");
      if (lane == 0)
        __hip_atomic_fetch_add(&ctrl[0], 1u, __ATOMIC_RELEASE, __HIP_MEMORY_SCOPE_WORKGROUP);
      if (w == 0) {
        while (__hip_atomic_load(&ctrl[0], __ATOMIC_ACQUIRE,
                                 __HIP_MEMORY_SCOPE_WORKGROUP) < 2u * (unsigned)(t + 1)) {}
        asm volatile("" ::: "memory");
        if (lane == 0)
          __hip_atomic_store(&fl[g * FSTRIDE], (unsigned)(t + 2),
                             __ATOMIC_RELAXED, __HIP_MEMORY_SCOPE_AGENT);
      }
    } else if (t + 1 < T_STEPS) {
      // ---- x-waves: gi(t+1), guarded by prev-layer flag (slot T-2-t) ----
      if (l > 0) {
        while (__hip_atomic_load(&fp[lane * FSTRIDE], __ATOMIC_RELAXED,
                                 __HIP_MEMORY_SCOPE_AGENT) < (unsigned)(t + 3)) {}
        asm volatile("" ::: "memory");
      }
      xgemv(t + 1);
    }
  }
}

// ---------- host ----------
extern "C" void kernel_launch(void* const* d_in, const int* in_sizes, int n_in,
                              void* d_out, int out_size, void* d_ws, size_t ws_size,
                              hipStream_t stream) {
  const float* x   = (const float*)d_in[0];
  const float* h0  = (const float*)d_in[1];
  const float* wih = (const float*)d_in[2];
  const float* whh = (const float*)d_in[3];
  const float* bih = (const float*)d_in[4];
  const float* bhh = (const float*)d_in[5];
  float* out = (float*)d_out;

  char* p = (char*)d_ws;
  unsigned short* xb    = (unsigned short*)p; p += (size_t)T_STEPS * SLOTE * 2;             // 33.6 MB
  unsigned short* wswhh = (unsigned short*)p; p += (size_t)LAYERS * WSZ * 2;                // 18.9 MB
  unsigned short* wswih = (unsigned short*)p; p += (size_t)LAYERS * WSZ * 2;                // 18.9 MB
  unsigned short* rings = (unsigned short*)p; p += (size_t)LAYERS * RING_SLOTS * SLOTE * 2; // 101 MB
  unsigned int*   flags = (unsigned int*)p;   p += 4096;  // 3*64*FSTRIDE*4 = 3 KB used
  // total ~172.5 MB

  static int attr_set = 0;
  if (!attr_set) {
    hipFuncSetAttribute((const void*)gru_fused,
                        hipFuncAttributeMaxDynamicSharedMemorySize, LDS_TOTAL);
    attr_set = 1;
  }

  hipMemsetAsync(flags, 0, 4096, stream);
  f2b_kernel<<<16384, 256, 0, stream>>>(x, xb, (T_STEPS * SLOTE) / 4);
  swizzle_w<<<4608, 256, 0, stream>>>(whh, wswhh);
  swizzle_w<<<4608, 256, 0, stream>>>(wih, wswih);

  gru_fused<<<LAYERS * 64, 256, LDS_TOTAL, stream>>>(
      xb, wswhh, wswih, bih, bhh, h0, rings, out, flags);
}

// Round 16
// 2400.000 us; speedup vs baseline: 1.6285x; 1.6285x over previous
//
#include <hip/hip_runtime.h>
#include <hip/hip_bf16.h>

typedef __attribute__((ext_vector_type(8))) short bf16x8;
typedef __attribute__((ext_vector_type(4))) float f32x4;

#define T_STEPS 256
#define BATCH   64
#define KDIM    1024
#define HDIM    1024
#define NGATE   3072   // 3*HDIM
#define LAYERS  3
#define SLOTE   (BATCH * HDIM)       // elements per h slot
#define RING_SLOTS (T_STEPS + 1)
#define WSZ     (192L * 32 * 64 * 8) // swizzled weight elems per layer
#define FSTRIDE 4                    // uints per flag (16 B padding)

#define LDS_BS_BYTES  65536                    // Whh r,z frags
#define LDS_WIS_BYTES 65536                    // Wih r,z frags
#define GI_PAR_FLOATS (3 * 64 * 20)            // padded [3][64][20] per parity
#define LDS_GI_BYTES  (2 * GI_PAR_FLOATS * 4)  // 30720 B
#define LDS_TOTAL (LDS_BS_BYTES + LDS_WIS_BYTES + LDS_GI_BYTES)  // 161792 <= 163840

#define MFMA16(a, b, c) __builtin_amdgcn_mfma_f32_16x16x32_bf16(a, b, c, 0, 0, 0)

// ---------- helpers (byte-identical to R6) ----------
__device__ __forceinline__ unsigned short f2b(float f) {
  union { float f; unsigned int u; } a; a.f = f;
  unsigned int u = a.u;
  unsigned int r = (u + 0x7FFFu + ((u >> 16) & 1u)) >> 16;  // RNE
  return (unsigned short)r;
}
__device__ __forceinline__ void gload16(const void* gptr, void* ldsptr) {
  __builtin_amdgcn_global_load_lds(
      (const __attribute__((address_space(1))) unsigned int*)gptr,
      (__attribute__((address_space(3))) unsigned int*)ldsptr,
      16, 0, 0);
}

// ---------- fp32 -> bf16 bulk convert (4 elems/thread) ----------
__global__ void f2b_kernel(const float* __restrict__ src,
                           unsigned short* __restrict__ dst, int n4) {
  int i = blockIdx.x * blockDim.x + threadIdx.x;
  if (i < n4) {
    float4 v = ((const float4*)src)[i];
    ushort4 o;
    o.x = f2b(v.x); o.y = f2b(v.y); o.z = f2b(v.z); o.w = f2b(v.w);
    ((ushort4*)dst)[i] = o;
  }
}

// ---------- swizzle a [3][3072][1024] fp32 matrix into MFMA frag layout ----------
// out: [l][ntile(192)][kc(32)][lane(64)][8 bf16]  (identical to R6..R14)
__global__ void swizzle_w(const float* __restrict__ w,
                          unsigned short* __restrict__ out) {
  long gid = (long)blockIdx.x * 256 + threadIdx.x;   // < 3*192*32*64
  int lane = (int)(gid & 63);
  long rest = gid >> 6;
  int kc = (int)(rest & 31); rest >>= 5;
  int ntile = (int)(rest % 192); int l = (int)(rest / 192);
  int n  = ntile * 16 + (lane & 15);
  int k0 = kc * 32 + (lane >> 4) * 8;
  const float* src = w + (((long)l * NGATE + n) * KDIM + k0);
  unsigned short o[8];
#pragma unroll
  for (int j = 0; j < 8; j++) o[j] = f2b(src[j]);
  bf16x8 v = *(bf16x8*)o;
  *(bf16x8*)(out + gid * 8) = v;
}

// ---------- fused 3-layer GRU, 192 wgs x 512 thr, wave-role specialized ----------
// R15 = R9 (best measured: 2234us) byte-identical EXCEPT gi buffer padded
// [3][64][16] -> [3][64][20] f32 (R12-verified: bank conflicts 1.65e7 ->
// 2.36e6, 7x; R12's regression was its sync restructure, absent here).
// Six structural variants of R9 all regressed (R10 +34%, R11 +9%, R12 +16%,
// R13 +52%, R14 +69%): R9's shape — 8 waves (4h+4x) at 2/SIMD, ONE barrier +
// ONE flag publish per step, gi in LDS, Whh r,z LDS + gate-n regs — is the
// measured local optimum; this round keeps it and removes only the verified
// bank-conflict cost.
__global__ __launch_bounds__(512, 2) void gru_fused(
    const unsigned short* __restrict__ xb,     // [T][64][1024] bf16 layer-0 input
    const unsigned short* __restrict__ wswhh,  // [3][WSZ] swizzled Whh
    const unsigned short* __restrict__ wswih,  // [3][WSZ] swizzled Wih
    const float* __restrict__ bih,             // [3][3072]
    const float* __restrict__ bhh,             // [3][3072]
    const float* __restrict__ h0,              // [3][64][1024]
    unsigned short* __restrict__ rings,        // [3][257][64*1024] bf16 (blocked slots)
    float* __restrict__ hout,                  // [3][64][1024] = d_out
    unsigned int* __restrict__ flags)          // [3][64][FSTRIDE], memset 0
{
  extern __shared__ __align__(16) char smem[];
  unsigned short* Bs  = (unsigned short*)smem;                       // [64][512]
  unsigned short* Wis = (unsigned short*)(smem + LDS_BS_BYTES);      // [64][512]
  float* gi_lds = (float*)(smem + LDS_BS_BYTES + LDS_WIS_BYTES);     // [2][3][64][20]

  int l = blockIdx.x >> 6, g = blockIdx.x & 63;
  int tid = threadIdx.x, wave = tid >> 6, lane = tid & 63;
  int lg = lane >> 4;
  int rg = wave & 3;                        // row-group for both roles
  bool is_h = (wave < 4);
  int row = rg * 16 + (lane & 15);          // batch row owned by this lane
  int cb  = g * 16 + lg * 4;                // first of 4 consecutive output cols

  const unsigned short* whh_l = wswhh + (size_t)l * WSZ;
  const unsigned short* wih_l = wswih + (size_t)l * WSZ;
  unsigned short* ring_l = rings + (size_t)l * RING_SLOTS * SLOTE;
  const unsigned short* prev_ring = rings + (size_t)(l - 1) * RING_SLOTS * SLOTE;
  unsigned int* fl = flags + (size_t)l * 64 * FSTRIDE;
  const unsigned int* fp = flags + (size_t)(l > 0 ? (l - 1) : 0) * 64 * FSTRIDE;

  // ---- stage Whh r,z (rows 0..63) and Wih r,z (rows 64..127) into LDS ----
#pragma unroll
  for (int i = 0; i < 16; i++) {
    int p = wave * 16 + i;                  // 0..127
    int gate = (p >> 5) & 1;                // 0=r,1=z within its matrix
    int kc = p & 31;
    const unsigned short* src = (p < 64)
        ? whh_l + ((((long)gate * 64 + g) * 32 + kc) * 64 + lane) * 8
        : wih_l + ((((long)gate * 64 + g) * 32 + kc) * 64 + lane) * 8;
    unsigned short* dst = (p < 64)
        ? &Bs[(size_t)p * 512 + (size_t)lane * 8]
        : &Wis[(size_t)(p - 64) * 512 + (size_t)lane * 8];
    gload16(src, dst);
  }

  // ---- gate-n weights into registers: Whh-n for h-waves, Wih-n for x-waves ----
  bf16x8 wn[32];
  {
    const unsigned short* base = is_h ? whh_l : wih_l;
#pragma unroll
    for (int kc = 0; kc < 32; kc++)
      wn[kc] = *(const bf16x8*)(base + ((((long)(2 * 64 + g)) * 32 + kc) * 64 + lane) * 8);
  }

  // ---- biases (h-waves only) ----
  float br_[4], bz_[4], bi_n[4], bh_n[4];
  float h[4] = {0.f, 0.f, 0.f, 0.f};
  if (is_h) {
    const float* bh_l = bhh + l * NGATE;
    const float* bi_l = bih + l * NGATE;
    float4 bhr4 = *(const float4*)(bh_l + 0 * HDIM + cb);
    float4 bhz4 = *(const float4*)(bh_l + 1 * HDIM + cb);
    float4 bhn4 = *(const float4*)(bh_l + 2 * HDIM + cb);
    float4 bir4 = *(const float4*)(bi_l + 0 * HDIM + cb);
    float4 biz4 = *(const float4*)(bi_l + 1 * HDIM + cb);
    float4 bin4 = *(const float4*)(bi_l + 2 * HDIM + cb);
    br_[0] = bir4.x + bhr4.x; br_[1] = bir4.y + bhr4.y; br_[2] = bir4.z + bhr4.z; br_[3] = bir4.w + bhr4.w;
    bz_[0] = biz4.x + bhz4.x; bz_[1] = biz4.y + bhz4.y; bz_[2] = biz4.z + bhz4.z; bz_[3] = biz4.w + bhz4.w;
    bi_n[0] = bin4.x; bi_n[1] = bin4.y; bi_n[2] = bin4.z; bi_n[3] = bin4.w;
    bh_n[0] = bhn4.x; bh_n[1] = bhn4.y; bh_n[2] = bhn4.z; bh_n[3] = bhn4.w;

    // ---- publish h(0)=h0 into own ring slot T (blocked, one 8B store) ----
    float4 h4 = *(const float4*)(h0 + (size_t)l * SLOTE + (size_t)row * HDIM + cb);
    h[0] = h4.x; h[1] = h4.y; h[2] = h4.z; h[3] = h4.w;
    union { unsigned short us[4]; unsigned long long u; } pk;
#pragma unroll
    for (int r = 0; r < 4; r++) pk.us[r] = f2b(h[r]);
    unsigned short* slotT = ring_l + (size_t)T_STEPS * SLOTE;
    __hip_atomic_store((unsigned long long*)(slotT + (size_t)g * 1024 + (size_t)row * 16 + lg * 4),
                       pk.u, __ATOMIC_RELAXED, __HIP_MEMORY_SCOPE_AGENT);
  }

  // ---- x-GEMV into local accs (role: x-waves). tt = step whose gi is computed ----
  f32x4 air, aiz, ain;
  auto xgemv = [&](int tt) {
    f32x4 z = {};
    air = z; aiz = z; ain = z;
    if (l == 0) {
      const unsigned short* xa_b = xb + (size_t)tt * SLOTE + (size_t)row * KDIM + lg * 8;
#pragma unroll
      for (int kb = 0; kb < 4; kb++) {
        bf16x8 xa[8];
#pragma unroll
        for (int j = 0; j < 8; j++)
          xa[j] = *(const bf16x8*)(xa_b + (size_t)(kb * 8 + j) * 32);
#pragma unroll
        for (int j = 0; j < 8; j++) {
          int kc = kb * 8 + j;
          bf16x8 wir = *(const bf16x8*)&Wis[(size_t)kc * 512 + (size_t)lane * 8];
          bf16x8 wiz = *(const bf16x8*)&Wis[(size_t)(32 + kc) * 512 + (size_t)lane * 8];
          air = MFMA16(wir, xa[j], air);
          aiz = MFMA16(wiz, xa[j], aiz);
          ain = MFMA16(wn[kc], xa[j], ain);
        }
      }
    } else {
      const unsigned short* xa_b = prev_ring + (size_t)(T_STEPS - 1 - tt) * SLOTE
                                   + (size_t)(lg >> 1) * 1024 + (size_t)row * 16 + (lg & 1) * 8;
#pragma unroll
      for (int kb = 0; kb < 4; kb++) {
        bf16x8 xa[8];
#pragma unroll
        for (int j = 0; j < 8; j++)
          xa[j] = *(const bf16x8*)(xa_b + (size_t)(kb * 8 + j) * 2048);
#pragma unroll
        for (int j = 0; j < 8; j++) {
          int kc = kb * 8 + j;
          bf16x8 wir = *(const bf16x8*)&Wis[(size_t)kc * 512 + (size_t)lane * 8];
          bf16x8 wiz = *(const bf16x8*)&Wis[(size_t)(32 + kc) * 512 + (size_t)lane * 8];
          air = MFMA16(wir, xa[j], air);
          aiz = MFMA16(wiz, xa[j], aiz);
          ain = MFMA16(wn[kc], xa[j], ain);
        }
      }
    }
    // write gi(tt) to LDS buffer tt&1: [gate][64 rows][20 pad] f32
    float* gp = gi_lds + (size_t)(tt & 1) * GI_PAR_FLOATS + (size_t)row * 20 + lg * 4;
    *(f32x4*)(gp + 0)    = air;
    *(f32x4*)(gp + 1280) = aiz;
    *(f32x4*)(gp + 2560) = ain;
  };

  __syncthreads();   // P1: staging vmcnt drained; h0 stores at LLC
  if (tid == 0)
    __hip_atomic_store(&fl[g * FSTRIDE], 1u, __ATOMIC_RELAXED, __HIP_MEMORY_SCOPE_AGENT);

  // ---- prologue: h-waves confirm all h0 published; x-waves compute gi(0) ----
  if (is_h) {
    while (__hip_atomic_load(&fl[lane * FSTRIDE], __ATOMIC_RELAXED,
                             __HIP_MEMORY_SCOPE_AGENT) < 1u) {}
    asm volatile("" ::: "memory");
  } else {
    if (l > 0) {
      while (__hip_atomic_load(&fp[lane * FSTRIDE], __ATOMIC_RELAXED,
                               __HIP_MEMORY_SCOPE_AGENT) < 2u) {}
      asm volatile("" ::: "memory");
    }
    xgemv(0);
  }
  __syncthreads();   // P2: gi(0) visible to h-waves

#pragma unroll 1
  for (int t = 0; t < T_STEPS; t++) {
    if (is_h) {
      // ---- h(t) B-frags from own slot (T-t), blocked layout ----
      const unsigned short* ha_b = ring_l + (size_t)(T_STEPS - t) * SLOTE
                                   + (size_t)(lg >> 1) * 1024 + (size_t)row * 16 + (lg & 1) * 8;
      f32x4 ahr = {}, ahz = {}, ahn = {};
#pragma unroll
      for (int kb = 0; kb < 4; kb++) {
        bf16x8 hh[8];
#pragma unroll
        for (int j = 0; j < 8; j++)
          hh[j] = *(const bf16x8*)(ha_b + (size_t)(kb * 8 + j) * 2048);
#pragma unroll
        for (int j = 0; j < 8; j++) {
          int kc = kb * 8 + j;
          bf16x8 whr = *(const bf16x8*)&Bs[(size_t)kc * 512 + (size_t)lane * 8];
          bf16x8 whz = *(const bf16x8*)&Bs[(size_t)(32 + kc) * 512 + (size_t)lane * 8];
          ahr = MFMA16(whr, hh[j], ahr);
          ahz = MFMA16(whz, hh[j], ahz);
          ahn = MFMA16(wn[kc], hh[j], ahn);
        }
      }
      // ---- gi(t) from LDS double buffer (padded stride) ----
      const float* gp = gi_lds + (size_t)(t & 1) * GI_PAR_FLOATS + (size_t)row * 20 + lg * 4;
      f32x4 xir = *(const f32x4*)(gp + 0);
      f32x4 xiz = *(const f32x4*)(gp + 1280);
      f32x4 xin = *(const f32x4*)(gp + 2560);
      // ---- gates + state update ----
      unsigned short* hn = ring_l + (size_t)(T_STEPS - 1 - t) * SLOTE;  // h(t+1)
      union { unsigned short us[4]; unsigned long long u; } pk;
#pragma unroll
      for (int r = 0; r < 4; r++) {
        float xr = xir[r] + ahr[r] + br_[r];
        float xz = xiz[r] + ahz[r] + bz_[r];
        float rr = 1.0f / (1.0f + __expf(-xr));
        float zz = 1.0f / (1.0f + __expf(-xz));
        float xn = (xin[r] + bi_n[r]) + rr * (ahn[r] + bh_n[r]);
        float e2 = __expf(-2.0f * xn);
        float nn = (1.0f - e2) / (1.0f + e2);    // tanh
        float hv = (1.0f - zz) * nn + zz * h[r];
        h[r] = hv;
        pk.us[r] = f2b(hv);
      }
      __hip_atomic_store((unsigned long long*)(hn + (size_t)g * 1024 + (size_t)row * 16 + lg * 4),
                         pk.u, __ATOMIC_RELAXED, __HIP_MEMORY_SCOPE_AGENT);
      if (t == T_STEPS - 1) {
        float4 o; o.x = h[0]; o.y = h[1]; o.z = h[2]; o.w = h[3];
        *(float4*)(hout + (size_t)l * SLOTE + (size_t)row * HDIM + cb) = o;
      }
    } else if (t + 1 < T_STEPS) {
      // ---- x-waves: gi(t+1), guarded by prev-layer flag (slot T-2-t) ----
      if (l > 0) {
        while (__hip_atomic_load(&fp[lane * FSTRIDE], __ATOMIC_RELAXED,
                                 __HIP_MEMORY_SCOPE_AGENT) < (unsigned)(t + 3)) {}
        asm volatile("" ::: "memory");
      }
      xgemv(t + 1);
    }

    __syncthreads();   // B1 (uniform): h stores drained; gi(t+1) visible next iter

    if (is_h) {
      if (tid == 0)
        __hip_atomic_store(&fl[g * FSTRIDE], (unsigned)(t + 2),
                           __ATOMIC_RELAXED, __HIP_MEMORY_SCOPE_AGENT);
      if (t + 1 < T_STEPS) {
        while (__hip_atomic_load(&fl[lane * FSTRIDE], __ATOMIC_RELAXED,
                                 __HIP_MEMORY_SCOPE_AGENT) < (unsigned)(t + 2)) {}
        asm volatile("" ::: "memory");
      }
    }
  }
}

// ---------- host ----------
extern "C" void kernel_launch(void* const* d_in, const int* in_sizes, int n_in,
                              void* d_out, int out_size, void* d_ws, size_t ws_size,
                              hipStream_t stream) {
  const float* x   = (const float*)d_in[0];
  const float* h0  = (const float*)d_in[1];
  const float* wih = (const float*)d_in[2];
  const float* whh = (const float*)d_in[3];
  const float* bih = (const float*)d_in[4];
  const float* bhh = (const float*)d_in[5];
  float* out = (float*)d_out;

  char* p = (char*)d_ws;
  unsigned short* xb    = (unsigned short*)p; p += (size_t)T_STEPS * SLOTE * 2;             // 33.6 MB
  unsigned short* wswhh = (unsigned short*)p; p += (size_t)LAYERS * WSZ * 2;                // 18.9 MB
  unsigned short* wswih = (unsigned short*)p; p += (size_t)LAYERS * WSZ * 2;                // 18.9 MB
  unsigned short* rings = (unsigned short*)p; p += (size_t)LAYERS * RING_SLOTS * SLOTE * 2; // 101 MB
  unsigned int*   flags = (unsigned int*)p;   p += 4096;  // 3*64*FSTRIDE*4 = 3 KB used
  // total ~172.5 MB

  static int attr_set = 0;
  if (!attr_set) {
    hipFuncSetAttribute((const void*)gru_fused,
                        hipFuncAttributeMaxDynamicSharedMemorySize, LDS_TOTAL);
    attr_set = 1;
  }

  hipMemsetAsync(flags, 0, 4096, stream);
  f2b_kernel<<<16384, 256, 0, stream>>>(x, xb, (T_STEPS * SLOTE) / 4);
  swizzle_w<<<4608, 256, 0, stream>>>(whh, wswhh);
  swizzle_w<<<4608, 256, 0, stream>>>(wih, wswih);

  gru_fused<<<LAYERS * 64, 512, LDS_TOTAL, stream>>>(
      xb, wswhh, wswih, bih, bhh, h0, rings, out, flags);
}